// Round 13
// baseline (1016.074 us; speedup 1.0000x reference)
//
#include <hip/hip_runtime.h>
#include <hip/hip_bf16.h>
#include <math.h>

#define B_  32
#define T1_ 128
#define L1_ 543
#define T2_ 543
#define VOCAB_ 32000
#define XCH_ 272   // lstm2: x rows resident in LDS per chunk (2 chunks cover T2_)

typedef __attribute__((ext_vector_type(8))) short bf16x8;
typedef __attribute__((ext_vector_type(4))) float f32x4;
typedef unsigned short ushort_t;

__device__ __forceinline__ short f2bf(float f){
    union { float f; unsigned u; } v; v.f = f;
    unsigned r = v.u + 0x7FFFu + ((v.u >> 16) & 1u);
    return (short)(r >> 16);
}
// sigmoid: __expf (compiler-generated trans op, hazards handled) + rcp BUILTIN
// (not inline asm — rounds 5-8 showed hand-emitted trans asm NaNs).
__device__ __forceinline__ float fsig(float x){
    return __builtin_amdgcn_rcpf(1.0f + __expf(-x));
}

// ================= prepack Wh1/Wx1/b1 into MFMA B-fragment layout (bf16), UNSCALED =================
__global__ __launch_bounds__(256) void pack_B1(
    const float* __restrict__ Wh1,  // (3,64,256)
    const float* __restrict__ Wx1,  // (3,3,256)
    const float* __restrict__ b1,   // (256)
    short* __restrict__ Bp)         // 7*16*64*8 shorts
{
    int id = blockIdx.x*256 + threadIdx.x;
    if (id >= 7*16*64) return;
    int kt  = id >> 10;
    int rem = id & 1023;
    int nt  = rem >> 6;
    int lane= rem & 63;
    int j = nt*16 + (lane & 15);
    int g = lane >> 4;
    bf16x8 o;
    #pragma unroll
    for (int i=0;i<8;++i){
        int kl = 8*g + i;
        float v = 0.f;
        if (kt < 6){
            int tap = kt >> 1, ch = (kt & 1)*32 + kl;
            v = Wh1[(tap*64 + ch)*256 + j];
        } else {
            if (kl < 9){ int tap = kl/3, ch = kl - 3*tap; v = Wx1[(tap*3 + ch)*256 + j]; }
            else if (kl == 9) v = b1[j];
        }
        o[i] = f2bf(v);
    }
    *(bf16x8*)(Bp + (size_t)id*8) = o;
}

// ================= Stage 1: ConvLSTM1D #1, MFMA, EIGHT timesteps per launch (round-12 PASS verbatim) =================
// grid (8, 32), block 512 (8 waves). Chunk = 68 interior rows, halo 8.
// FIXED row<->l mapping: row r <-> l = l0-8+r. m-index u reads rows u..u+2, stores at row u+1.
// Valid trapezoid at sub-step s: rows [1+s, 83-s); s=7 -> [8,76) = exact interior.
// TILE-5 SKIP: tile 5 (m 80..95) intersects valid m-range only for s<2.
__global__ __launch_bounds__(512) void lstm1_step8_mfma(
    const float* __restrict__ x,       // (B,128,543,3) fp32
    const short* __restrict__ Bp,      // packed B frags
    const ushort_t* __restrict__ h_in, // (B,543,64) bf16 = h(t-1)
    ushort_t* __restrict__ h_out,      // (B,543,64) bf16 = h(t+7)
    const float* __restrict__ c_in,    // (B,543,64) fp32 = c(t-1)
    float* __restrict__ c_out,         // (B,543,64) fp32 = c(t+7)
    int t)
{
    __shared__ short h0s[98*72];
    __shared__ short h1s[98*72];
    __shared__ short xs8[8*98*4];      // x(t..t+7), rows [0,98), 3ch+pad

    const int tid = threadIdx.x;
    const int wave = tid>>6, lane = tid&63, g = lane>>4, ln = lane&15;
    const int cq = wave&3, mgrp = wave>>2;
    const int b = blockIdx.y, l0 = blockIdx.x*68;
    const int ch = 16*cq + ln;
    const int mt0 = mgrp*3;            // tiles {0,1,2} or {3,4,5}

    // c(t-1) -> registers. Row = m-index + 1; valid rows [1,83).
    float cr[3][4];
    #pragma unroll
    for (int ti=0; ti<3; ++ti)
      #pragma unroll
      for (int rr=0; rr<4; ++rr){
        cr[ti][rr] = 0.f;
        int row = (mt0+ti)*16 + 4*g + rr + 1;
        int l = l0 - 8 + row;
        if (row < 83 && l >= 0 && l < L1_)
            cr[ti][rr] = c_in[((size_t)b*L1_ + l)*64 + ch];
      }

    // B fragments (shared by all 8 sub-steps)
    bf16x8 Bf[7][4];
    #pragma unroll
    for (int kt=0; kt<7; ++kt)
      #pragma unroll
      for (int gt=0; gt<4; ++gt)
        Bf[kt][gt] = *(const bf16x8*)(Bp + (size_t)(((kt*16 + (gt*4 + cq))*64) + lane)*8);

    // stage h(t-1) rows [0,84) -> h0s; zero h0s rows [84,98); zero ALL h1s
    const ushort_t* hb = h_in + (size_t)b*(L1_*64);
    for (int u=tid; u<84*8; u+=512){
        int row = u>>3, c8 = u&7;
        int l = l0 - 8 + row;
        uint4 v = make_uint4(0u,0u,0u,0u);
        if (l >= 0 && l < L1_) v = *(const uint4*)(hb + (size_t)l*64 + c8*8);
        *(uint4*)(h0s + row*72 + c8*8) = v;
    }
    for (int u=tid; u<504;  u+=512) ((int*)(h0s + 84*72))[u] = 0;
    for (int u=tid; u<3528; u+=512) ((int*)h1s)[u] = 0;
    // stage x(t..t+7), rows [0,98)
    const float* xb0 = x + ((size_t)b*T1_ + t)*(L1_*3);
    for (int u=tid; u<8*98*3; u+=512){
        int st = u/(98*3), rem = u - st*(98*3);
        int row = rem/3, c = rem - 3*row;
        int l = l0 - 8 + row;
        xs8[st*392 + row*4 + c] = f2bf((l>=0 && l<L1_) ? xb0[(size_t)st*(L1_*3) + l*3 + c] : 0.f);
    }
    __syncthreads();

    f32x4 zero4 = {0.f,0.f,0.f,0.f};
    for (int s=0; s<8; ++s){
        const short* src = (s&1) ? h1s : h0s;
        short*       dst = (s&1) ? h0s : h1s;
        const short* xv  = xs8 + s*392;

        f32x4 acc[3][4];
        #pragma unroll
        for (int ti=0; ti<3; ++ti)
          #pragma unroll
          for (int gt=0; gt<4; ++gt) acc[ti][gt] = zero4;

        #pragma unroll
        for (int ti=0; ti<3; ++ti){
            if (mt0+ti == 5 && s >= 2) continue;   // tile-5 skip (wave-uniform)
            const int rbase = (mt0+ti)*16 + ln;
            #pragma unroll
            for (int kt=0; kt<6; ++kt){
                int tap = kt >> 1;
                bf16x8 a = *(const bf16x8*)(src + (rbase + tap)*72 + (kt&1)*32 + 8*g);
                #pragma unroll
                for (int gt=0; gt<4; ++gt)
                    acc[ti][gt] = __builtin_amdgcn_mfma_f32_16x16x32_bf16(a, Bf[kt][gt], acc[ti][gt], 0,0,0);
            }
            bf16x8 a6;
            #pragma unroll
            for (int i=0;i<8;++i) a6[i] = 0;
            if (g == 0){
                #pragma unroll
                for (int i=0;i<8;++i){ int tap = i/3, c = i - 3*tap; a6[i] = xv[(rbase+tap)*4 + c]; }
            } else if (g == 1){
                a6[0] = xv[(rbase+2)*4 + 2];
                a6[1] = (short)0x3F80;
            }
            #pragma unroll
            for (int gt=0; gt<4; ++gt)
                acc[ti][gt] = __builtin_amdgcn_mfma_f32_16x16x32_bf16(a6, Bf[6][gt], acc[ti][gt], 0,0,0);
        }

        // gates: m-index u stored at row u+1; valid rows [1+s, 83-s), l in [0,543)
        #pragma unroll
        for (int ti=0; ti<3; ++ti)
          #pragma unroll
          for (int rr=0; rr<4; ++rr){
            int row = (mt0+ti)*16 + 4*g + rr + 1;
            int l = l0 - 8 + row;
            if (row >= 1+s && row < 83-s && l >= 0 && l < L1_){
                float iv = fsig(acc[ti][0][rr]);
                float fv = fsig(acc[ti][1][rr]);
                float gv = fmaxf(acc[ti][2][rr], 0.f);
                float ov = fsig(acc[ti][3][rr]);
                float cv = fv*cr[ti][rr] + iv*gv;
                cr[ti][rr] = cv;
                float hv = ov * fmaxf(cv, 0.f);
                if (s < 7){
                    dst[row*72 + ch] = f2bf(hv);
                } else {
                    size_t idx = ((size_t)b*L1_ + l)*64 + ch;
                    c_out[idx] = cv;
                    h_out[idx] = (ushort_t)f2bf(hv);
                }
            }
          }
        if (s < 7) __syncthreads();
    }
}

// ================= Stage 2: ConvLSTM1D #2, MFMA, persistent, double-buffered h =================
// DELTA vs round-12 PASS: ALL x rows staged in LDS (2 chunks of 272/271, one mid-scan restage)
// -> ZERO in-loop global loads. Rationale: the compiler emits s_waitcnt vmcnt(0) before every
// s_barrier; the per-step x prefetch load left HBM latency exposed at 543 barriers.
// hs double-buffer, gates, MFMA layout unchanged.
__global__ __launch_bounds__(512) void lstm2_mfma(
    const ushort_t* __restrict__ x2, // (B,543,64) bf16
    const float* __restrict__ Wh2,   // (3,32,128)
    const float* __restrict__ Wx2,   // (3,1,128)
    const float* __restrict__ b2,    // (128)
    float* __restrict__ out)         // (B,64,32)
{
    __shared__ short hs[2][66*40];   // 10560 B
    __shared__ short xall[XCH_*66];  // 35904 B; row t: [0]=0, [1..64]=x[t][0..63], [65]=0
    const int tid = threadIdx.x;
    const int wave = tid>>6, lane = tid&63, g = lane>>4, ln = lane&15;
    const int s = wave&3, q = wave>>2;
    const int b = blockIdx.x;

    bf16x8 Bf[4][4];
    #pragma unroll
    for (int gi=0; gi<4; ++gi){
        int j = (2*gi + q)*16 + ln;
        #pragma unroll
        for (int kt=0; kt<3; ++kt){
            bf16x8 o;
            #pragma unroll
            for (int i=0;i<8;++i) o[i] = f2bf(Wh2[(kt*32 + 8*g + i)*128 + j]);
            Bf[kt][gi] = o;
        }
        bf16x8 o;
        #pragma unroll
        for (int i=0;i<8;++i) o[i] = 0;
        if (g==0){
            o[0]=f2bf(Wx2[0*128+j]); o[1]=f2bf(Wx2[1*128+j]); o[2]=f2bf(Wx2[2*128+j]);
            o[3]=f2bf(b2[j]);
        }
        Bf[3][gi] = o;
    }

    const ushort_t* xb = x2 + (size_t)b*(T2_*64);

    for (int i=tid; i<2640; i+=512) ((int*)hs)[i] = 0;   // both h buffers (incl. halo rows)
    // stage x chunk 0: rows [0, XCH_)
    for (int u=tid; u<XCH_*66; u+=512){
        int tt = u/66, p = u - tt*66;
        short v = 0;
        if (p >= 1 && p < 65) v = (short)xb[tt*64 + p - 1];
        xall[u] = v;
    }
    float creg[4];
    #pragma unroll
    for (int i=0;i<4;++i) creg[i]=0.f;
    __syncthreads();

    const int lA = 16*s + ln;
    const int chn = 16*q + ln;

    for (int t=0; t<T2_; ++t){
        if (t == XCH_){
            // restage chunk 1: rows [XCH_, T2_). Prior step's reads completed before its
            // bottom barrier; one barrier after makes writes visible. ONE exposed HBM drain total.
            for (int u=tid; u<(T2_-XCH_)*66; u+=512){
                int tt = u/66, p = u - tt*66;
                short v = 0;
                if (p >= 1 && p < 65) v = (short)xb[(size_t)(XCH_+tt)*64 + p - 1];
                xall[u] = v;
            }
            __syncthreads();
        }
        const int cur = t & 1, nxt = cur ^ 1;
        const short* xrow = xall + (t < XCH_ ? t : t - XCH_)*66;

        f32x4 acc[4];
        f32x4 zero4 = {0.f,0.f,0.f,0.f};
        #pragma unroll
        for (int gi=0; gi<4; ++gi) acc[gi] = zero4;

        #pragma unroll
        for (int kt=0; kt<3; ++kt){
            bf16x8 a = *(const bf16x8*)(&hs[cur][0] + (lA + kt)*40 + 8*g);
            #pragma unroll
            for (int gi=0; gi<4; ++gi)
                acc[gi] = __builtin_amdgcn_mfma_f32_16x16x32_bf16(a, Bf[kt][gi], acc[gi], 0,0,0);
        }
        {
            bf16x8 a3;
            #pragma unroll
            for (int i=0;i<8;++i) a3[i] = 0;
            if (g==0){
                a3[0]=xrow[lA]; a3[1]=xrow[lA+1]; a3[2]=xrow[lA+2];
                a3[3]=(short)0x3F80;
            }
            #pragma unroll
            for (int gi=0; gi<4; ++gi)
                acc[gi] = __builtin_amdgcn_mfma_f32_16x16x32_bf16(a3, Bf[3][gi], acc[gi], 0,0,0);
        }

        #pragma unroll
        for (int r=0; r<4; ++r){
            int l = 16*s + 4*g + r;
            float iv = fsig(acc[0][r]);
            float fv = fsig(acc[1][r]);
            float gv = fmaxf(acc[2][r], 0.f);
            float ov = fsig(acc[3][r]);
            float cv = fv*creg[r] + iv*gv;
            creg[r] = cv;
            float hv = ov * fmaxf(cv, 0.f);
            hs[nxt][(1+l)*40 + chn] = f2bf(hv);
            if (t == T2_-1) out[(size_t)b*2048 + l*32 + chn] = hv;
        }
        if (t+1 < T2_) __syncthreads();   // nxt writes visible; last iter needs no barrier
    }
}

// ================= Transformer decoder, 1 WG per batch =================
__global__ __launch_bounds__(256) void decoder_kernel(
    const float* __restrict__ xin,
    const float* __restrict__ Wq, const float* __restrict__ bq,
    const float* __restrict__ Wk, const float* __restrict__ bk,
    const float* __restrict__ Wv, const float* __restrict__ bv,
    const float* __restrict__ Wo, const float* __restrict__ bo,
    const float* __restrict__ g1, const float* __restrict__ be1,
    const float* __restrict__ W1, const float* __restrict__ bf1,
    const float* __restrict__ W2, const float* __restrict__ bf2,
    const float* __restrict__ g2, const float* __restrict__ be2,
    float* __restrict__ xout)
{
    __shared__ float smem[16384];
    float* sx  = smem;
    float* sq  = smem + 2048;
    float* sk  = smem + 4096;
    float* sv  = smem + 6144;
    float* so  = smem + 8192;
    float* sy  = smem + 10240;
    float* sff = smem + 12288;

    const int b = blockIdx.x;
    const int tid = threadIdx.x;

    for (int i=tid; i<2048; i+=256) sx[i] = xin[(size_t)b*2048 + i];
    __syncthreads();

    for (int i=tid; i<2048; i+=256){
        int s = i >> 5, j = i & 31;
        float aq = bq[j], ak = bk[j], av = bv[j];
        for (int d=0; d<32; ++d){
            float xv = sx[s*32+d];
            aq = fmaf(xv, Wq[d*32+j], aq);
            ak = fmaf(xv, Wk[d*32+j], ak);
            av = fmaf(xv, Wv[d*32+j], av);
        }
        sq[i]=aq; sk[i]=ak; sv[i]=av;
    }
    __syncthreads();

    if (tid < 128){
        int h = tid >> 6, si = tid & 63;
        const int o = h*16;
        float qv[16];
        #pragma unroll
        for (int kk=0; kk<16; ++kk) qv[kk] = sq[si*32 + o + kk];
        float mx = -1e30f;
        for (int ti=0; ti<=si; ++ti){
            float sc = 0.f;
            #pragma unroll
            for (int kk=0; kk<16; ++kk) sc = fmaf(qv[kk], sk[ti*32+o+kk], sc);
            mx = fmaxf(mx, sc*0.25f);
        }
        float sum = 0.f;
        float accv[16];
        #pragma unroll
        for (int kk=0; kk<16; ++kk) accv[kk]=0.f;
        for (int ti=0; ti<=si; ++ti){
            float sc = 0.f;
            #pragma unroll
            for (int kk=0; kk<16; ++kk) sc = fmaf(qv[kk], sk[ti*32+o+kk], sc);
            float p = expf(sc*0.25f - mx);
            sum += p;
            #pragma unroll
            for (int kk=0; kk<16; ++kk) accv[kk] = fmaf(p, sv[ti*32+o+kk], accv[kk]);
        }
        float inv = 1.f/sum;
        #pragma unroll
        for (int kk=0; kk<16; ++kk) so[si*32 + o + kk] = accv[kk]*inv;
    }
    __syncthreads();

    for (int i=tid; i<2048; i+=256){
        int s = i>>5, d = i&31;
        float a = bo[d];
        for (int j=0; j<32; ++j) a = fmaf(so[s*32+j], Wo[j*32+d], a);
        sy[i] = sx[i] + a;
    }
    __syncthreads();
    if (tid < 64){
        float mu=0.f;
        for (int d=0; d<32; ++d) mu += sy[tid*32+d];
        mu *= (1.f/32.f);
        float var=0.f;
        for (int d=0; d<32; ++d){ float dd = sy[tid*32+d]-mu; var = fmaf(dd,dd,var); }
        var *= (1.f/32.f);
        float rs = rsqrtf(var + 1e-5f);
        for (int d=0; d<32; ++d) sy[tid*32+d] = (sy[tid*32+d]-mu)*rs*g1[d] + be1[d];
    }
    __syncthreads();
    for (int i=tid; i<4096; i+=256){
        int s = i>>6, ff = i&63;
        float a = bf1[ff];
        for (int d=0; d<32; ++d) a = fmaf(sy[s*32+d], W1[d*64+ff], a);
        sff[i] = fmaxf(a, 0.f);
    }
    __syncthreads();
    for (int i=tid; i<2048; i+=256){
        int s=i>>5, d=i&31;
        float a = bf2[d];
        for (int ff=0; ff<64; ++ff) a = fmaf(sff[s*64+ff], W2[ff*32+d], a);
        sx[i] = sy[i] + a;
    }
    __syncthreads();
    if (tid < 64){
        float mu=0.f;
        for (int d=0; d<32; ++d) mu += sx[tid*32+d];
        mu *= (1.f/32.f);
        float var=0.f;
        for (int d=0; d<32; ++d){ float dd = sx[tid*32+d]-mu; var = fmaf(dd,dd,var); }
        var *= (1.f/32.f);
        float rs = rsqrtf(var + 1e-5f);
        for (int d=0; d<32; ++d)
            xout[(size_t)b*2048 + tid*32 + d] = (sx[tid*32+d]-mu)*rs*g2[d] + be2[d];
    }
}

// ================= Vocab head: 128-row x 1024-col tiles, float4 Wd/out, 512 WGs (2/CU) =================
__global__ __launch_bounds__(256) void head_kernel(
    const float* __restrict__ xin,  // (2048, 32)
    const float* __restrict__ Wd,   // (32, 32000)
    const float* __restrict__ bd,   // (32000)
    float* __restrict__ out)        // (2048, 32000)
{
    __shared__ float sx[128*32];    // 16 KB
    const int r0 = blockIdx.y * 128;
    const int c0 = blockIdx.x * 1024;
    const int tid = threadIdx.x;
    for (int u=tid; u<128*8; u+=256){
        int row = u>>3, c8 = u&7;
        *(float4*)(sx + row*32 + c8*4) = *(const float4*)(xin + (size_t)(r0+row)*32 + c8*4);
    }
    __syncthreads();
    int c = c0 + tid*4;
    if (c >= VOCAB_) return;
    float4 w[32];
    #pragma unroll
    for (int d=0; d<32; ++d) w[d] = *(const float4*)(Wd + (size_t)d*VOCAB_ + c);
    const float4 b4 = *(const float4*)(bd + c);
    for (int r=0; r<128; ++r){
        const float* xr = sx + r*32;
        float a0=b4.x, a1=b4.y, a2=b4.z, a3=b4.w;
        #pragma unroll
        for (int d=0; d<32; ++d){
            float xv = xr[d];      // same addr across lanes -> LDS broadcast
            a0 = fmaf(xv, w[d].x, a0);
            a1 = fmaf(xv, w[d].y, a1);
            a2 = fmaf(xv, w[d].z, a2);
            a3 = fmaf(xv, w[d].w, a3);
        }
        *reinterpret_cast<float4*>(&out[(size_t)(r0+r)*VOCAB_ + c]) = make_float4(a0,a1,a2,a3);
    }
}

// ================= launch =================
extern "C" void kernel_launch(void* const* d_in, const int* in_sizes, int n_in,
                              void* d_out, int out_size, void* d_ws, size_t ws_size,
                              hipStream_t stream)
{
    const float* x   = (const float*)d_in[0];
    const float* Wx1 = (const float*)d_in[1];
    const float* Wh1 = (const float*)d_in[2];
    const float* b1  = (const float*)d_in[3];
    const float* Wx2 = (const float*)d_in[4];
    const float* Wh2 = (const float*)d_in[5];
    const float* b2  = (const float*)d_in[6];
    const float* Wq  = (const float*)d_in[7];
    const float* bq  = (const float*)d_in[8];
    const float* Wk  = (const float*)d_in[9];
    const float* bk  = (const float*)d_in[10];
    const float* Wv  = (const float*)d_in[11];
    const float* bv  = (const float*)d_in[12];
    const float* Wo  = (const float*)d_in[13];
    const float* bo  = (const float*)d_in[14];
    const float* g1  = (const float*)d_in[15];
    const float* be1 = (const float*)d_in[16];
    const float* W1  = (const float*)d_in[17];
    const float* bf1 = (const float*)d_in[18];
    const float* W2  = (const float*)d_in[19];
    const float* bf2 = (const float*)d_in[20];
    const float* g2  = (const float*)d_in[21];
    const float* be2 = (const float*)d_in[22];
    const float* Wd  = (const float*)d_in[23];
    const float* bd  = (const float*)d_in[24];

    const size_t nH = (size_t)B_ * L1_ * 64;    // 1,112,064 elements per state buffer
    float* ws = (float*)d_ws;
    size_t ws_floats = ws_size / sizeof(float);
    float* x3 = ws;                          // 65536 floats
    float* x4 = ws + 65536;                  // 65536 floats
    short* Bp = (short*)(ws + 131072);       // 57344 shorts = 28672 floats
    const size_t base_f = 131072 + 28672;
    const size_t need_f = base_f + nH + 2*nH; // 2 bf16 bufs + 2 f32 bufs
    float* statebase;
    if (ws_floats >= need_f) statebase = ws + base_f;
    else                     statebase = (float*)d_out;    // 262MB scratch, consumed before head writes
    ushort_t* h1a = (ushort_t*)statebase;                  // nH bf16
    ushort_t* h1b = h1a + nH;                              // nH bf16
    float*    c1a = (float*)(h1b + nH);                    // nH f32
    float*    c1b = c1a + nH;                              // nH f32

    hipMemsetAsync(h1a, 0, nH*sizeof(ushort_t), stream);
    hipMemsetAsync(c1a, 0, nH*sizeof(float), stream);

    pack_B1<<<28, 256, 0, stream>>>(Wh1, Wx1, b1, Bp);

    ushort_t *hcur = h1a, *hnxt = h1b;
    float    *ccur = c1a, *cnxt = c1b;
    for (int t=0; t<T1_; t+=8){
        lstm1_step8_mfma<<<dim3(8, B_), 512, 0, stream>>>(x, Bp, hcur, hnxt, ccur, cnxt, t);
        ushort_t* th = hcur; hcur = hnxt; hnxt = th;
        float*    tc = ccur; ccur = cnxt; cnxt = tc;
    }
    lstm2_mfma<<<dim3(B_), 512, 0, stream>>>(hcur, Wh2, Wx2, b2, x3);
    decoder_kernel<<<dim3(B_), 256, 0, stream>>>(x3, Wq,bq,Wk,bk,Wv,bv,Wo,bo,
                                                 g1,be1,W1,bf1,W2,bf2,g2,be2, x4);
    head_kernel<<<dim3(32, 16), 256, 0, stream>>>(x4, Wd, bd, (float*)d_out);
}

// Round 14
// 967.562 us; speedup vs baseline: 1.0501x; 1.0501x over previous
//
#include <hip/hip_runtime.h>
#include <hip/hip_bf16.h>
#include <math.h>

#define B_  32
#define T1_ 128
#define L1_ 543
#define T2_ 543
#define VOCAB_ 32000

typedef __attribute__((ext_vector_type(8))) short bf16x8;
typedef __attribute__((ext_vector_type(4))) float f32x4;
typedef unsigned short ushort_t;

__device__ __forceinline__ short f2bf(float f){
    union { float f; unsigned u; } v; v.f = f;
    unsigned r = v.u + 0x7FFFu + ((v.u >> 16) & 1u);
    return (short)(r >> 16);
}
// sigmoid: __expf (compiler-generated trans op, hazards handled) + rcp BUILTIN
// (not inline asm — rounds 5-8 showed hand-emitted trans asm NaNs).
__device__ __forceinline__ float fsig(float x){
    return __builtin_amdgcn_rcpf(1.0f + __expf(-x));
}

// ================= prepack Wh1/Wx1/b1 into MFMA B-fragment layout (bf16), UNSCALED =================
__global__ __launch_bounds__(256) void pack_B1(
    const float* __restrict__ Wh1,  // (3,64,256)
    const float* __restrict__ Wx1,  // (3,3,256)
    const float* __restrict__ b1,   // (256)
    short* __restrict__ Bp)         // 7*16*64*8 shorts
{
    int id = blockIdx.x*256 + threadIdx.x;
    if (id >= 7*16*64) return;
    int kt  = id >> 10;
    int rem = id & 1023;
    int nt  = rem >> 6;
    int lane= rem & 63;
    int j = nt*16 + (lane & 15);
    int g = lane >> 4;
    bf16x8 o;
    #pragma unroll
    for (int i=0;i<8;++i){
        int kl = 8*g + i;
        float v = 0.f;
        if (kt < 6){
            int tap = kt >> 1, ch = (kt & 1)*32 + kl;
            v = Wh1[(tap*64 + ch)*256 + j];
        } else {
            if (kl < 9){ int tap = kl/3, ch = kl - 3*tap; v = Wx1[(tap*3 + ch)*256 + j]; }
            else if (kl == 9) v = b1[j];
        }
        o[i] = f2bf(v);
    }
    *(bf16x8*)(Bp + (size_t)id*8) = o;
}

// ================= Stage 1: ConvLSTM1D #1, MFMA, EIGHT timesteps per launch (round-12 PASS verbatim) =================
// grid (8, 32), block 512 (8 waves). Chunk = 68 interior rows, halo 8.
// FIXED row<->l mapping: row r <-> l = l0-8+r. m-index u reads rows u..u+2, stores at row u+1.
// Valid trapezoid at sub-step s: rows [1+s, 83-s); s=7 -> [8,76) = exact interior.
// TILE-5 SKIP: tile 5 (m 80..95) intersects valid m-range only for s<2.
__global__ __launch_bounds__(512) void lstm1_step8_mfma(
    const float* __restrict__ x,       // (B,128,543,3) fp32
    const short* __restrict__ Bp,      // packed B frags
    const ushort_t* __restrict__ h_in, // (B,543,64) bf16 = h(t-1)
    ushort_t* __restrict__ h_out,      // (B,543,64) bf16 = h(t+7)
    const float* __restrict__ c_in,    // (B,543,64) fp32 = c(t-1)
    float* __restrict__ c_out,         // (B,543,64) fp32 = c(t+7)
    int t)
{
    __shared__ short h0s[98*72];
    __shared__ short h1s[98*72];
    __shared__ short xs8[8*98*4];      // x(t..t+7), rows [0,98), 3ch+pad

    const int tid = threadIdx.x;
    const int wave = tid>>6, lane = tid&63, g = lane>>4, ln = lane&15;
    const int cq = wave&3, mgrp = wave>>2;
    const int b = blockIdx.y, l0 = blockIdx.x*68;
    const int ch = 16*cq + ln;
    const int mt0 = mgrp*3;            // tiles {0,1,2} or {3,4,5}

    // c(t-1) -> registers. Row = m-index + 1; valid rows [1,83).
    float cr[3][4];
    #pragma unroll
    for (int ti=0; ti<3; ++ti)
      #pragma unroll
      for (int rr=0; rr<4; ++rr){
        cr[ti][rr] = 0.f;
        int row = (mt0+ti)*16 + 4*g + rr + 1;
        int l = l0 - 8 + row;
        if (row < 83 && l >= 0 && l < L1_)
            cr[ti][rr] = c_in[((size_t)b*L1_ + l)*64 + ch];
      }

    // B fragments (shared by all 8 sub-steps)
    bf16x8 Bf[7][4];
    #pragma unroll
    for (int kt=0; kt<7; ++kt)
      #pragma unroll
      for (int gt=0; gt<4; ++gt)
        Bf[kt][gt] = *(const bf16x8*)(Bp + (size_t)(((kt*16 + (gt*4 + cq))*64) + lane)*8);

    // stage h(t-1) rows [0,84) -> h0s; zero h0s rows [84,98); zero ALL h1s
    const ushort_t* hb = h_in + (size_t)b*(L1_*64);
    for (int u=tid; u<84*8; u+=512){
        int row = u>>3, c8 = u&7;
        int l = l0 - 8 + row;
        uint4 v = make_uint4(0u,0u,0u,0u);
        if (l >= 0 && l < L1_) v = *(const uint4*)(hb + (size_t)l*64 + c8*8);
        *(uint4*)(h0s + row*72 + c8*8) = v;
    }
    for (int u=tid; u<504;  u+=512) ((int*)(h0s + 84*72))[u] = 0;
    for (int u=tid; u<3528; u+=512) ((int*)h1s)[u] = 0;
    // stage x(t..t+7), rows [0,98)
    const float* xb0 = x + ((size_t)b*T1_ + t)*(L1_*3);
    for (int u=tid; u<8*98*3; u+=512){
        int st = u/(98*3), rem = u - st*(98*3);
        int row = rem/3, c = rem - 3*row;
        int l = l0 - 8 + row;
        xs8[st*392 + row*4 + c] = f2bf((l>=0 && l<L1_) ? xb0[(size_t)st*(L1_*3) + l*3 + c] : 0.f);
    }
    __syncthreads();

    f32x4 zero4 = {0.f,0.f,0.f,0.f};
    for (int s=0; s<8; ++s){
        const short* src = (s&1) ? h1s : h0s;
        short*       dst = (s&1) ? h0s : h1s;
        const short* xv  = xs8 + s*392;

        f32x4 acc[3][4];
        #pragma unroll
        for (int ti=0; ti<3; ++ti)
          #pragma unroll
          for (int gt=0; gt<4; ++gt) acc[ti][gt] = zero4;

        #pragma unroll
        for (int ti=0; ti<3; ++ti){
            if (mt0+ti == 5 && s >= 2) continue;   // tile-5 skip (wave-uniform)
            const int rbase = (mt0+ti)*16 + ln;
            #pragma unroll
            for (int kt=0; kt<6; ++kt){
                int tap = kt >> 1;
                bf16x8 a = *(const bf16x8*)(src + (rbase + tap)*72 + (kt&1)*32 + 8*g);
                #pragma unroll
                for (int gt=0; gt<4; ++gt)
                    acc[ti][gt] = __builtin_amdgcn_mfma_f32_16x16x32_bf16(a, Bf[kt][gt], acc[ti][gt], 0,0,0);
            }
            bf16x8 a6;
            #pragma unroll
            for (int i=0;i<8;++i) a6[i] = 0;
            if (g == 0){
                #pragma unroll
                for (int i=0;i<8;++i){ int tap = i/3, c = i - 3*tap; a6[i] = xv[(rbase+tap)*4 + c]; }
            } else if (g == 1){
                a6[0] = xv[(rbase+2)*4 + 2];
                a6[1] = (short)0x3F80;
            }
            #pragma unroll
            for (int gt=0; gt<4; ++gt)
                acc[ti][gt] = __builtin_amdgcn_mfma_f32_16x16x32_bf16(a6, Bf[6][gt], acc[ti][gt], 0,0,0);
        }

        // gates: m-index u stored at row u+1; valid rows [1+s, 83-s), l in [0,543)
        #pragma unroll
        for (int ti=0; ti<3; ++ti)
          #pragma unroll
          for (int rr=0; rr<4; ++rr){
            int row = (mt0+ti)*16 + 4*g + rr + 1;
            int l = l0 - 8 + row;
            if (row >= 1+s && row < 83-s && l >= 0 && l < L1_){
                float iv = fsig(acc[ti][0][rr]);
                float fv = fsig(acc[ti][1][rr]);
                float gv = fmaxf(acc[ti][2][rr], 0.f);
                float ov = fsig(acc[ti][3][rr]);
                float cv = fv*cr[ti][rr] + iv*gv;
                cr[ti][rr] = cv;
                float hv = ov * fmaxf(cv, 0.f);
                if (s < 7){
                    dst[row*72 + ch] = f2bf(hv);
                } else {
                    size_t idx = ((size_t)b*L1_ + l)*64 + ch;
                    c_out[idx] = cv;
                    h_out[idx] = (ushort_t)f2bf(hv);
                }
            }
          }
        if (s < 7) __syncthreads();
    }
}

// ================= Stage 2: ConvLSTM1D #2, MFMA, persistent, double-buffered (round-12 PASS verbatim) =================
__global__ __launch_bounds__(512) void lstm2_mfma(
    const ushort_t* __restrict__ x2, // (B,543,64) bf16
    const float* __restrict__ Wh2,   // (3,32,128)
    const float* __restrict__ Wx2,   // (3,1,128)
    const float* __restrict__ b2,    // (128)
    float* __restrict__ out)         // (B,64,32)
{
    __shared__ short hs[2][66*40];
    __shared__ short xs2[2][66];
    const int tid = threadIdx.x;
    const int wave = tid>>6, lane = tid&63, g = lane>>4, ln = lane&15;
    const int s = wave&3, q = wave>>2;
    const int b = blockIdx.x;

    bf16x8 Bf[4][4];
    #pragma unroll
    for (int gi=0; gi<4; ++gi){
        int j = (2*gi + q)*16 + ln;
        #pragma unroll
        for (int kt=0; kt<3; ++kt){
            bf16x8 o;
            #pragma unroll
            for (int i=0;i<8;++i) o[i] = f2bf(Wh2[(kt*32 + 8*g + i)*128 + j]);
            Bf[kt][gi] = o;
        }
        bf16x8 o;
        #pragma unroll
        for (int i=0;i<8;++i) o[i] = 0;
        if (g==0){
            o[0]=f2bf(Wx2[0*128+j]); o[1]=f2bf(Wx2[1*128+j]); o[2]=f2bf(Wx2[2*128+j]);
            o[3]=f2bf(b2[j]);
        }
        Bf[3][gi] = o;
    }

    const ushort_t* xb = x2 + (size_t)b*(T2_*64);

    for (int i=tid; i<2640; i+=512) ((int*)hs)[i] = 0;
    if (tid < 66){
        xs2[1][tid] = 0;
        short v = 0;
        if (tid >= 1 && tid < 65) v = (short)xb[tid - 1];
        xs2[0][tid] = v;
    }
    float creg[4];
    #pragma unroll
    for (int i=0;i<4;++i) creg[i]=0.f;

    ushort_t xreg = (tid < 64) ? xb[64 + tid] : (ushort_t)0;
    __syncthreads();

    const int lA = 16*s + ln;
    const int chn = 16*q + ln;

    for (int t=0; t<T2_; ++t){
        const int cur = t & 1, nxt = cur ^ 1;
        if (tid < 64 && t+1 < T2_) xs2[nxt][1+tid] = (short)xreg;
        if (tid < 64 && t+2 < T2_) xreg = xb[(size_t)(t+2)*64 + tid];

        f32x4 acc[4];
        f32x4 zero4 = {0.f,0.f,0.f,0.f};
        #pragma unroll
        for (int gi=0; gi<4; ++gi) acc[gi] = zero4;

        #pragma unroll
        for (int kt=0; kt<3; ++kt){
            bf16x8 a = *(const bf16x8*)(&hs[cur][0] + (lA + kt)*40 + 8*g);
            #pragma unroll
            for (int gi=0; gi<4; ++gi)
                acc[gi] = __builtin_amdgcn_mfma_f32_16x16x32_bf16(a, Bf[kt][gi], acc[gi], 0,0,0);
        }
        {
            bf16x8 a3;
            #pragma unroll
            for (int i=0;i<8;++i) a3[i] = 0;
            if (g==0){
                a3[0]=xs2[cur][lA]; a3[1]=xs2[cur][lA+1]; a3[2]=xs2[cur][lA+2];
                a3[3]=(short)0x3F80;
            }
            #pragma unroll
            for (int gi=0; gi<4; ++gi)
                acc[gi] = __builtin_amdgcn_mfma_f32_16x16x32_bf16(a3, Bf[3][gi], acc[gi], 0,0,0);
        }

        #pragma unroll
        for (int r=0; r<4; ++r){
            int l = 16*s + 4*g + r;
            float iv = fsig(acc[0][r]);
            float fv = fsig(acc[1][r]);
            float gv = fmaxf(acc[2][r], 0.f);
            float ov = fsig(acc[3][r]);
            float cv = fv*creg[r] + iv*gv;
            creg[r] = cv;
            float hv = ov * fmaxf(cv, 0.f);
            hs[nxt][(1+l)*40 + chn] = f2bf(hv);
            if (t == T2_-1) out[(size_t)b*2048 + l*32 + chn] = hv;
        }
        __syncthreads();
    }
}

// ================= Transformer decoder, 1 WG per batch =================
__global__ __launch_bounds__(256) void decoder_kernel(
    const float* __restrict__ xin,
    const float* __restrict__ Wq, const float* __restrict__ bq,
    const float* __restrict__ Wk, const float* __restrict__ bk,
    const float* __restrict__ Wv, const float* __restrict__ bv,
    const float* __restrict__ Wo, const float* __restrict__ bo,
    const float* __restrict__ g1, const float* __restrict__ be1,
    const float* __restrict__ W1, const float* __restrict__ bf1,
    const float* __restrict__ W2, const float* __restrict__ bf2,
    const float* __restrict__ g2, const float* __restrict__ be2,
    float* __restrict__ xout)
{
    __shared__ float smem[16384];
    float* sx  = smem;
    float* sq  = smem + 2048;
    float* sk  = smem + 4096;
    float* sv  = smem + 6144;
    float* so  = smem + 8192;
    float* sy  = smem + 10240;
    float* sff = smem + 12288;

    const int b = blockIdx.x;
    const int tid = threadIdx.x;

    for (int i=tid; i<2048; i+=256) sx[i] = xin[(size_t)b*2048 + i];
    __syncthreads();

    for (int i=tid; i<2048; i+=256){
        int s = i >> 5, j = i & 31;
        float aq = bq[j], ak = bk[j], av = bv[j];
        for (int d=0; d<32; ++d){
            float xv = sx[s*32+d];
            aq = fmaf(xv, Wq[d*32+j], aq);
            ak = fmaf(xv, Wk[d*32+j], ak);
            av = fmaf(xv, Wv[d*32+j], av);
        }
        sq[i]=aq; sk[i]=ak; sv[i]=av;
    }
    __syncthreads();

    if (tid < 128){
        int h = tid >> 6, si = tid & 63;
        const int o = h*16;
        float qv[16];
        #pragma unroll
        for (int kk=0; kk<16; ++kk) qv[kk] = sq[si*32 + o + kk];
        float mx = -1e30f;
        for (int ti=0; ti<=si; ++ti){
            float sc = 0.f;
            #pragma unroll
            for (int kk=0; kk<16; ++kk) sc = fmaf(qv[kk], sk[ti*32+o+kk], sc);
            mx = fmaxf(mx, sc*0.25f);
        }
        float sum = 0.f;
        float accv[16];
        #pragma unroll
        for (int kk=0; kk<16; ++kk) accv[kk]=0.f;
        for (int ti=0; ti<=si; ++ti){
            float sc = 0.f;
            #pragma unroll
            for (int kk=0; kk<16; ++kk) sc = fmaf(qv[kk], sk[ti*32+o+kk], sc);
            float p = expf(sc*0.25f - mx);
            sum += p;
            #pragma unroll
            for (int kk=0; kk<16; ++kk) accv[kk] = fmaf(p, sv[ti*32+o+kk], accv[kk]);
        }
        float inv = 1.f/sum;
        #pragma unroll
        for (int kk=0; kk<16; ++kk) so[si*32 + o + kk] = accv[kk]*inv;
    }
    __syncthreads();

    for (int i=tid; i<2048; i+=256){
        int s = i>>5, d = i&31;
        float a = bo[d];
        for (int j=0; j<32; ++j) a = fmaf(so[s*32+j], Wo[j*32+d], a);
        sy[i] = sx[i] + a;
    }
    __syncthreads();
    if (tid < 64){
        float mu=0.f;
        for (int d=0; d<32; ++d) mu += sy[tid*32+d];
        mu *= (1.f/32.f);
        float var=0.f;
        for (int d=0; d<32; ++d){ float dd = sy[tid*32+d]-mu; var = fmaf(dd,dd,var); }
        var *= (1.f/32.f);
        float rs = rsqrtf(var + 1e-5f);
        for (int d=0; d<32; ++d) sy[tid*32+d] = (sy[tid*32+d]-mu)*rs*g1[d] + be1[d];
    }
    __syncthreads();
    for (int i=tid; i<4096; i+=256){
        int s = i>>6, ff = i&63;
        float a = bf1[ff];
        for (int d=0; d<32; ++d) a = fmaf(sy[s*32+d], W1[d*64+ff], a);
        sff[i] = fmaxf(a, 0.f);
    }
    __syncthreads();
    for (int i=tid; i<2048; i+=256){
        int s=i>>5, d=i&31;
        float a = bf2[d];
        for (int ff=0; ff<64; ++ff) a = fmaf(sff[s*64+ff], W2[ff*32+d], a);
        sx[i] = sy[i] + a;
    }
    __syncthreads();
    if (tid < 64){
        float mu=0.f;
        for (int d=0; d<32; ++d) mu += sx[tid*32+d];
        mu *= (1.f/32.f);
        float var=0.f;
        for (int d=0; d<32; ++d){ float dd = sx[tid*32+d]-mu; var = fmaf(dd,dd,var); }
        var *= (1.f/32.f);
        float rs = rsqrtf(var + 1e-5f);
        for (int d=0; d<32; ++d)
            xout[(size_t)b*2048 + tid*32 + d] = (sx[tid*32+d]-mu)*rs*g2[d] + be2[d];
    }
}

// ================= Vocab head: 128-row x 1024-col tiles, float4 Wd/out, 512 WGs (2/CU) =================
__global__ __launch_bounds__(256) void head_kernel(
    const float* __restrict__ xin,  // (2048, 32)
    const float* __restrict__ Wd,   // (32, 32000)
    const float* __restrict__ bd,   // (32000)
    float* __restrict__ out)        // (2048, 32000)
{
    __shared__ float sx[128*32];    // 16 KB
    const int r0 = blockIdx.y * 128;
    const int c0 = blockIdx.x * 1024;
    const int tid = threadIdx.x;
    for (int u=tid; u<128*8; u+=256){
        int row = u>>3, c8 = u&7;
        *(float4*)(sx + row*32 + c8*4) = *(const float4*)(xin + (size_t)(r0+row)*32 + c8*4);
    }
    __syncthreads();
    int c = c0 + tid*4;
    if (c >= VOCAB_) return;
    float4 w[32];
    #pragma unroll
    for (int d=0; d<32; ++d) w[d] = *(const float4*)(Wd + (size_t)d*VOCAB_ + c);
    const float4 b4 = *(const float4*)(bd + c);
    for (int r=0; r<128; ++r){
        const float* xr = sx + r*32;
        float a0=b4.x, a1=b4.y, a2=b4.z, a3=b4.w;
        #pragma unroll
        for (int d=0; d<32; ++d){
            float xv = xr[d];      // same addr across lanes -> LDS broadcast
            a0 = fmaf(xv, w[d].x, a0);
            a1 = fmaf(xv, w[d].y, a1);
            a2 = fmaf(xv, w[d].z, a2);
            a3 = fmaf(xv, w[d].w, a3);
        }
        *reinterpret_cast<float4*>(&out[(size_t)(r0+r)*VOCAB_ + c]) = make_float4(a0,a1,a2,a3);
    }
}

// ================= launch =================
extern "C" void kernel_launch(void* const* d_in, const int* in_sizes, int n_in,
                              void* d_out, int out_size, void* d_ws, size_t ws_size,
                              hipStream_t stream)
{
    const float* x   = (const float*)d_in[0];
    const float* Wx1 = (const float*)d_in[1];
    const float* Wh1 = (const float*)d_in[2];
    const float* b1  = (const float*)d_in[3];
    const float* Wx2 = (const float*)d_in[4];
    const float* Wh2 = (const float*)d_in[5];
    const float* b2  = (const float*)d_in[6];
    const float* Wq  = (const float*)d_in[7];
    const float* bq  = (const float*)d_in[8];
    const float* Wk  = (const float*)d_in[9];
    const float* bk  = (const float*)d_in[10];
    const float* Wv  = (const float*)d_in[11];
    const float* bv  = (const float*)d_in[12];
    const float* Wo  = (const float*)d_in[13];
    const float* bo  = (const float*)d_in[14];
    const float* g1  = (const float*)d_in[15];
    const float* be1 = (const float*)d_in[16];
    const float* W1  = (const float*)d_in[17];
    const float* bf1 = (const float*)d_in[18];
    const float* W2  = (const float*)d_in[19];
    const float* bf2 = (const float*)d_in[20];
    const float* g2  = (const float*)d_in[21];
    const float* be2 = (const float*)d_in[22];
    const float* Wd  = (const float*)d_in[23];
    const float* bd  = (const float*)d_in[24];

    const size_t nH = (size_t)B_ * L1_ * 64;    // 1,112,064 elements per state buffer
    float* ws = (float*)d_ws;
    size_t ws_floats = ws_size / sizeof(float);
    float* x3 = ws;                          // 65536 floats
    float* x4 = ws + 65536;                  // 65536 floats
    short* Bp = (short*)(ws + 131072);       // 57344 shorts = 28672 floats
    const size_t base_f = 131072 + 28672;
    const size_t need_f = base_f + nH + 2*nH; // 2 bf16 bufs + 2 f32 bufs
    float* statebase;
    if (ws_floats >= need_f) statebase = ws + base_f;
    else                     statebase = (float*)d_out;    // 262MB scratch, consumed before head writes
    ushort_t* h1a = (ushort_t*)statebase;                  // nH bf16
    ushort_t* h1b = h1a + nH;                              // nH bf16
    float*    c1a = (float*)(h1b + nH);                    // nH f32
    float*    c1b = c1a + nH;                              // nH f32

    hipMemsetAsync(h1a, 0, nH*sizeof(ushort_t), stream);
    hipMemsetAsync(c1a, 0, nH*sizeof(float), stream);

    pack_B1<<<28, 256, 0, stream>>>(Wh1, Wx1, b1, Bp);

    ushort_t *hcur = h1a, *hnxt = h1b;
    float    *ccur = c1a, *cnxt = c1b;
    for (int t=0; t<T1_; t+=8){
        lstm1_step8_mfma<<<dim3(8, B_), 512, 0, stream>>>(x, Bp, hcur, hnxt, ccur, cnxt, t);
        ushort_t* th = hcur; hcur = hnxt; hnxt = th;
        float*    tc = ccur; ccur = cnxt; cnxt = tc;
    }
    lstm2_mfma<<<dim3(B_), 512, 0, stream>>>(hcur, Wh2, Wx2, b2, x3);
    decoder_kernel<<<dim3(B_), 256, 0, stream>>>(x3, Wq,bq,Wk,bk,Wv,bv,Wo,bo,
                                                 g1,be1,W1,bf1,W2,bf2,g2,be2, x4);
    head_kernel<<<dim3(32, 16), 256, 0, stream>>>(x4, Wd, bd, (float*)d_out);
}